// Round 2
// baseline (1134.689 us; speedup 1.0000x reference)
//
#include <hip/hip_runtime.h>
#include <hip/hip_bf16.h>

#define DI __device__ __forceinline__

typedef short bf16x8 __attribute__((ext_vector_type(8)));
typedef float f32x4 __attribute__((ext_vector_type(4)));
using bf16 = __hip_bfloat16;

constexpr int Tn = 16384, Sn = 256, En = 1024;
constexpr float SCALEF = 0.08838834764831845f;   // 128^-0.5
constexpr float CLAMPF = 50000.0f;

DI f32x4 mfma16(bf16x8 a, bf16x8 b, f32x4 c) {
  return __builtin_amdgcn_mfma_f32_16x16x32_bf16(a, b, c, 0, 0, 0);
}
DI unsigned short f2bu(float x) { bf16 h = __float2bfloat16(x); return *(unsigned short*)&h; }
DI unsigned int pack2(float lo, float hi) { return (unsigned)f2bu(lo) | ((unsigned)f2bu(hi) << 16); }
DI bf16x8 ldg8(const bf16* p) { return *(const bf16x8*)p; }
DI float clampf(float v) { return fminf(fmaxf(v, -CLAMPF), CLAMPF); }

// ---------------- casts ----------------
__global__ void cast_f32_bf16_v4(const float* __restrict__ in, bf16* __restrict__ out, int n4) {
  int i = blockIdx.x * 256 + threadIdx.x;
  if (i >= n4) return;
  float4 f = reinterpret_cast<const float4*>(in)[i];
  unsigned long long u = (unsigned long long)pack2(f.x, f.y) |
                         ((unsigned long long)pack2(f.z, f.w) << 32);
  *reinterpret_cast<unsigned long long*>(out + (size_t)i * 4) = u;
}

// y=0: l cast; y=1..6: weight transpose+cast W[K][N] -> Wt[N][K]
__global__ void cast_misc(const float* __restrict__ l, bf16* __restrict__ lb,
                          const float* __restrict__ w0, bf16* __restrict__ o0,
                          const float* __restrict__ w1, bf16* __restrict__ o1,
                          const float* __restrict__ w2, bf16* __restrict__ o2,
                          const float* __restrict__ w3, bf16* __restrict__ o3,
                          const float* __restrict__ w4, bf16* __restrict__ o4,
                          const float* __restrict__ w5, bf16* __restrict__ o5) {
  int id = blockIdx.x * 256 + threadIdx.x;
  switch (blockIdx.y) {
    case 0: if (id < 1024*768) lb[id] = __float2bfloat16(l[id]); break;
    case 1: if (id < 256*1024) { int k = id >> 10, n = id & 1023; o0[n*256 + k] = __float2bfloat16(w0[id]); } break;
    case 2: if (id < 256*1024) { int k = id >> 10, n = id & 1023; o1[n*256 + k] = __float2bfloat16(w1[id]); } break;
    case 3: if (id < 768*1024) { int k = id >> 10, n = id & 1023; o2[n*768 + k] = __float2bfloat16(w2[id]); } break;
    case 4: if (id < 768*1024) { int k = id >> 10, n = id & 1023; o3[n*768 + k] = __float2bfloat16(w3[id]); } break;
    case 5: if (id < 1024*256) { int k = id >> 8,  n = id & 255;  o4[n*1024 + k] = __float2bfloat16(w4[id]); } break;
    case 6: if (id < 1024*768) { int k = id / 768, n = id % 768;  o5[n*1024 + k] = __float2bfloat16(w5[id]); } break;
  }
}

// ---------------- generic 128x128 MFMA GEMM ----------------
// A [M][K] bf16 row-major; Bw [N][K] bf16 (pre-transposed weights).
// z = blockIdx.z + zbase selects {Bw0,bias0,out0} vs {Bw1,bias1,out1}.
// MODE 0 (per-b): M=16384,K=256 -> z0: qh_b natural (+bias)*SCALE; z1: valvT_b transposed (+bias)
// MODE 1: M=1024, K=768 -> z0: kh natural (full);  z1: vallT transposed (full)
// MODE 2 (per-b): M=16384,K=1024,N=256 -> f32 out + bias
// MODE 3: M=1024, K=1024,N=768 -> f32 out + bias
template<int MODE>
__global__ __launch_bounds__(256) void gemm_kern(
    const bf16* __restrict__ A, const bf16* __restrict__ Bw0, const bf16* __restrict__ Bw1,
    const float* __restrict__ bias0, const float* __restrict__ bias1,
    void* __restrict__ out0, void* __restrict__ out1, int zbase)
{
  constexpr int K = (MODE == 0) ? 256 : (MODE == 1) ? 768 : 1024;
  const int z = blockIdx.z + zbase;
  const bf16* Bw = z ? Bw1 : Bw0;
  const float* bias = z ? bias1 : bias0;
  const int m0 = blockIdx.x * 128, n0 = blockIdx.y * 128;
  const int tid = threadIdx.x, lane = tid & 63;
  const int w = tid >> 6, wm = w >> 1, wn = w & 1;
  const int l15 = lane & 15, l4 = lane >> 4;

  __shared__ bf16 smem[128 * 136];          // staging uses first 32KB; epilogue reuses all
  bf16* As = smem;
  bf16* Bs = smem + 128 * 64;

  f32x4 acc[4][4];
  #pragma unroll
  for (int a = 0; a < 4; a++)
    #pragma unroll
    for (int c = 0; c < 4; c++) acc[a][c] = f32x4{0.f, 0.f, 0.f, 0.f};

  for (int k0 = 0; k0 < K; k0 += 64) {
    __syncthreads();
    #pragma unroll
    for (int it = 0; it < 4; it++) {
      int cid = it * 256 + tid;           // 0..1023
      int row = cid >> 3, chk = cid & 7;  // 16B chunk within 128B row
      uint4 va = *reinterpret_cast<const uint4*>(A  + (size_t)(m0 + row) * K + k0 + chk * 8);
      *reinterpret_cast<uint4*>(As + row * 64 + ((chk ^ (row & 7)) * 8)) = va;
      uint4 vb = *reinterpret_cast<const uint4*>(Bw + (size_t)(n0 + row) * K + k0 + chk * 8);
      *reinterpret_cast<uint4*>(Bs + row * 64 + ((chk ^ (row & 7)) * 8)) = vb;
    }
    __syncthreads();
    #pragma unroll
    for (int ks = 0; ks < 2; ks++) {
      bf16x8 af[4], bfr[4];
      #pragma unroll
      for (int mf = 0; mf < 4; mf++) {
        int r = wm * 64 + mf * 16 + l15;
        af[mf] = *(const bf16x8*)(As + r * 64 + (((ks * 4 + l4) ^ (r & 7)) * 8));
      }
      #pragma unroll
      for (int nf = 0; nf < 4; nf++) {
        int r = wn * 64 + nf * 16 + l15;
        bfr[nf] = *(const bf16x8*)(Bs + r * 64 + (((ks * 4 + l4) ^ (r & 7)) * 8));
      }
      #pragma unroll
      for (int mf = 0; mf < 4; mf++)
        #pragma unroll
        for (int nf = 0; nf < 4; nf++)
          acc[mf][nf] = mfma16(af[mf], bfr[nf], acc[mf][nf]);
    }
  }
  __syncthreads();

  if constexpr (MODE <= 1) {
    // bias (+scale) -> bf16 LDS tile [128 m][136 n]
    #pragma unroll
    for (int nf = 0; nf < 4; nf++) {
      int nl = wn * 64 + nf * 16 + l15;
      float bv = bias[n0 + nl];
      #pragma unroll
      for (int mf = 0; mf < 4; mf++) {
        int ml = wm * 64 + mf * 16 + l4 * 4;
        #pragma unroll
        for (int i = 0; i < 4; i++) {
          float vv = acc[mf][nf][i] + bv;
          if (MODE == 0 && z == 0) vv *= SCALEF;
          smem[(ml + i) * 136 + nl] = __float2bfloat16(vv);
        }
      }
    }
    __syncthreads();
    constexpr int TT = (MODE == 0) ? Tn : Sn;
    const int h = n0 >> 7;                     // 128-wide n-tile = one head
    const int r2 = tid >> 1, c0 = (tid & 1) * 64;
    if (z == 0) {
      // natural [bh][token][d]  (per-b for MODE 0: bq=0)
      int m = m0 + r2;
      int bq = (MODE == 0) ? 0 : (m >> 8);
      int t  = m & (TT - 1);
      bf16* out = (bf16*)out0;
      size_t base = ((size_t)(bq * 8 + h) * TT + t) * 128 + c0;
      #pragma unroll
      for (int j = 0; j < 32; j++) {
        unsigned int u = *(const unsigned int*)(smem + r2 * 136 + c0 + 2 * j);
        *(unsigned int*)(out + base + 2 * j) = u;
      }
    } else {
      // transposed [bh][d][token]
      int bq = (MODE == 0) ? 0 : (m0 >> 8);
      int t0 = m0 & (TT - 1);
      bf16* out = (bf16*)out1;
      size_t base = ((size_t)(bq * 8 + h) * 128 + r2) * TT + t0 + c0;
      #pragma unroll
      for (int j = 0; j < 32; j++) {
        unsigned short u0 = *(const unsigned short*)(smem + (c0 + 2 * j)     * 136 + r2);
        unsigned short u1 = *(const unsigned short*)(smem + (c0 + 2 * j + 1) * 136 + r2);
        *(unsigned int*)(out + base + 2 * j) = (unsigned)u0 | ((unsigned)u1 << 16);
      }
    }
  } else {
    constexpr int NOUT = (MODE == 2) ? 256 : 768;
    float* out = (float*)out0;
    #pragma unroll
    for (int nf = 0; nf < 4; nf++) {
      int n = n0 + wn * 64 + nf * 16 + l15;
      float bv = bias[n];
      #pragma unroll
      for (int mf = 0; mf < 4; mf++) {
        size_t mbase = (size_t)(m0 + wm * 64 + mf * 16 + l4 * 4) * NOUT + n;
        #pragma unroll
        for (int i = 0; i < 4; i++)
          out[mbase + (size_t)i * NOUT] = acc[mf][nf][i] + bv;
      }
    }
  }
}

// ---------------- attention row pass (per-b): row softmax + out_v tile + col partials ----
__global__ __launch_bounds__(256) void attn_row(
    const bf16* __restrict__ qh,      // [8][Tn][128]
    const bf16* __restrict__ kh,      // [8][Sn][128]
    const bf16* __restrict__ vallT,   // [8][128][Sn]
    bf16* __restrict__ ovh,           // [Tn][En]
    float* __restrict__ cmax_part, float* __restrict__ csum_part)  // [8*256][256]
{
  const int tb = blockIdx.x, h = blockIdx.y;
  const int tbase = tb * 64;
  const int tid = threadIdx.x, lane = tid & 63, w = tid >> 6;
  const int l15 = lane & 15, l4 = lane >> 4;

  __shared__ bf16 P[64 * 264];     // [64 t][256 s + 8 pad]
  __shared__ float red[4][64];

  const bf16* qp = qh + (size_t)h * Tn * 128;
  const bf16* kp = kh + (size_t)h * Sn * 128;

  f32x4 acc[4][4];
  #pragma unroll
  for (int a = 0; a < 4; a++)
    #pragma unroll
    for (int c = 0; c < 4; c++) acc[a][c] = f32x4{0.f, 0.f, 0.f, 0.f};

  // scores [64 t][wave's 64 s]
  #pragma unroll
  for (int ks = 0; ks < 4; ks++) {
    const int dof = ks * 32 + l4 * 8;
    bf16x8 aq[4], bk[4];
    #pragma unroll
    for (int ti = 0; ti < 4; ti++) aq[ti] = ldg8(qp + (size_t)(tbase + ti * 16 + l15) * 128 + dof);
    #pragma unroll
    for (int si = 0; si < 4; si++) bk[si] = ldg8(kp + (size_t)(w * 64 + si * 16 + l15) * 128 + dof);
    #pragma unroll
    for (int ti = 0; ti < 4; ti++)
      #pragma unroll
      for (int si = 0; si < 4; si++)
        acc[ti][si] = mfma16(aq[ti], bk[si], acc[ti][si]);
  }
  #pragma unroll
  for (int ti = 0; ti < 4; ti++)
    #pragma unroll
    for (int si = 0; si < 4; si++)
      #pragma unroll
      for (int i = 0; i < 4; i++) acc[ti][si][i] = clampf(acc[ti][si][i]);

  // column partial stats over this tile's 64 t (waves own disjoint s)
  #pragma unroll
  for (int si = 0; si < 4; si++) {
    float cmv = -3.4e38f;
    #pragma unroll
    for (int ti = 0; ti < 4; ti++)
      #pragma unroll
      for (int i = 0; i < 4; i++) cmv = fmaxf(cmv, acc[ti][si][i]);
    cmv = fmaxf(cmv, __shfl_xor(cmv, 16));
    cmv = fmaxf(cmv, __shfl_xor(cmv, 32));
    float cs = 0.f;
    #pragma unroll
    for (int ti = 0; ti < 4; ti++)
      #pragma unroll
      for (int i = 0; i < 4; i++) cs += __expf(acc[ti][si][i] - cmv);
    cs += __shfl_xor(cs, 16);
    cs += __shfl_xor(cs, 32);
    if (lane < 16) {
      const int s = w * 64 + si * 16 + lane;
      cmax_part[((size_t)h * 256 + s) * 256 + tb] = cmv;
      csum_part[((size_t)h * 256 + s) * 256 + tb] = cs;
    }
  }

  // row max (cross-wave via LDS)
  float rst[4][4];
  #pragma unroll
  for (int ti = 0; ti < 4; ti++)
    #pragma unroll
    for (int i = 0; i < 4; i++) {
      float m2 = fmaxf(fmaxf(acc[ti][0][i], acc[ti][1][i]), fmaxf(acc[ti][2][i], acc[ti][3][i]));
      #pragma unroll
      for (int off = 1; off < 16; off <<= 1) m2 = fmaxf(m2, __shfl_xor(m2, off));
      rst[ti][i] = m2;
    }
  if (l15 == 0) {
    #pragma unroll
    for (int ti = 0; ti < 4; ti++)
      #pragma unroll
      for (int i = 0; i < 4; i++) red[w][ti * 16 + l4 * 4 + i] = rst[ti][i];
  }
  __syncthreads();
  #pragma unroll
  for (int ti = 0; ti < 4; ti++)
    #pragma unroll
    for (int i = 0; i < 4; i++) {
      const int tl = ti * 16 + l4 * 4 + i;
      rst[ti][i] = fmaxf(fmaxf(red[0][tl], red[1][tl]), fmaxf(red[2][tl], red[3][tl]));
    }
  __syncthreads();

  // exp + row sum
  float rsm[4][4];
  #pragma unroll
  for (int ti = 0; ti < 4; ti++)
    #pragma unroll
    for (int i = 0; i < 4; i++) {
      float s = 0.f;
      #pragma unroll
      for (int si = 0; si < 4; si++) {
        float e = __expf(acc[ti][si][i] - rst[ti][i]);
        acc[ti][si][i] = e;
        s += e;
      }
      #pragma unroll
      for (int off = 1; off < 16; off <<= 1) s += __shfl_xor(s, off);
      rsm[ti][i] = s;
    }
  if (l15 == 0) {
    #pragma unroll
    for (int ti = 0; ti < 4; ti++)
      #pragma unroll
      for (int i = 0; i < 4; i++) red[w][ti * 16 + l4 * 4 + i] = rsm[ti][i];
  }
  __syncthreads();
  #pragma unroll
  for (int ti = 0; ti < 4; ti++)
    #pragma unroll
    for (int i = 0; i < 4; i++) {
      const int tl = ti * 16 + l4 * 4 + i;
      rsm[ti][i] = 1.0f / (red[0][tl] + red[1][tl] + red[2][tl] + red[3][tl]);
    }

  // normalized P -> LDS bf16
  #pragma unroll
  for (int ti = 0; ti < 4; ti++)
    #pragma unroll
    for (int si = 0; si < 4; si++)
      #pragma unroll
      for (int i = 0; i < 4; i++)
        P[(ti * 16 + l4 * 4 + i) * 264 + w * 64 + si * 16 + l15] =
            __float2bfloat16(acc[ti][si][i] * rsm[ti][i]);
  __syncthreads();

  // out_v = P @ val_l ; wave owns d-range w*32..w*32+31
  f32x4 oacc[4][2];
  #pragma unroll
  for (int a = 0; a < 4; a++)
    #pragma unroll
    for (int c = 0; c < 2; c++) oacc[a][c] = f32x4{0.f, 0.f, 0.f, 0.f};
  #pragma unroll
  for (int ks2 = 0; ks2 < 8; ks2++) {
    const int soff = ks2 * 32 + l4 * 8;
    bf16x8 bv[2];
    #pragma unroll
    for (int nf = 0; nf < 2; nf++)
      bv[nf] = ldg8(vallT + ((size_t)h * 128 + w * 32 + nf * 16 + l15) * Sn + soff);
    #pragma unroll
    for (int ti = 0; ti < 4; ti++) {
      bf16x8 ap = *(const bf16x8*)(P + (ti * 16 + l15) * 264 + soff);
      #pragma unroll
      for (int nf = 0; nf < 2; nf++)
        oacc[ti][nf] = mfma16(ap, bv[nf], oacc[ti][nf]);
    }
  }
  // ovh [t][e]
  #pragma unroll
  for (int ti = 0; ti < 4; ti++)
    #pragma unroll
    for (int nf = 0; nf < 2; nf++) {
      const int d = w * 32 + nf * 16 + l15;
      size_t base = (size_t)(tbase + ti * 16 + l4 * 4) * En + h * 128 + d;
      #pragma unroll
      for (int i = 0; i < 4; i++) ovh[base + (size_t)i * En] = __float2bfloat16(oacc[ti][nf][i]);
    }
}

// ---------------- column-stat reduction (per-b): [8*256 s][256 tb] -> max, 1/sum -------
__global__ __launch_bounds__(256) void col_reduce(
    const float* __restrict__ cmax_part, const float* __restrict__ csum_part,
    float* __restrict__ cmax, float* __restrict__ cinv)
{
  int gw = blockIdx.x * 4 + (threadIdx.x >> 6);   // (h*256+s)
  int lane = threadIdx.x & 63;
  const float4 mv = reinterpret_cast<const float4*>(cmax_part + (size_t)gw * 256)[lane];
  float m = fmaxf(fmaxf(mv.x, mv.y), fmaxf(mv.z, mv.w));
  #pragma unroll
  for (int off = 1; off < 64; off <<= 1) m = fmaxf(m, __shfl_xor(m, off));
  const float4 sv = reinterpret_cast<const float4*>(csum_part + (size_t)gw * 256)[lane];
  float s = sv.x * __expf(mv.x - m) + sv.y * __expf(mv.y - m) +
            sv.z * __expf(mv.z - m) + sv.w * __expf(mv.w - m);
  #pragma unroll
  for (int off = 1; off < 64; off <<= 1) s += __shfl_xor(s, off);
  if (lane == 0) { cmax[gw] = m; cinv[gw] = 1.0f / s; }
}

// ---------------- attention column pass (per-b): out_l -------------------------------
__global__ __launch_bounds__(256) void attn_col(
    const bf16* __restrict__ qh, const bf16* __restrict__ kh, const bf16* __restrict__ valvT,
    const float* __restrict__ cmax, const float* __restrict__ cinv,
    float* __restrict__ olh)   // [256 s][1024 e], pre-zeroed, atomicAdd
{
  const int chunk = blockIdx.x, h = blockIdx.y, zs = blockIdx.z;
  const int tid = threadIdx.x, lane = tid & 63, w = tid >> 6;
  const int l15 = lane & 15, l4 = lane >> 4;
  const int sbase = zs * 128 + w * 32;           // wave owns 32 s-columns

  __shared__ bf16 PT[4][32 * 72];                // per wave: [32 s][64 t + 8 pad]

  const bf16* qp = qh + (size_t)h * Tn * 128;
  const bf16* kp = kh + (size_t)h * Sn * 128;
  const bf16* vp = valvT + (size_t)h * 128 * Tn;

  float cm[2], ci[2];
  #pragma unroll
  for (int si = 0; si < 2; si++) {
    const int s = sbase + si * 16 + l15;
    cm[si] = cmax[h * 256 + s];
    ci[si] = cinv[h * 256 + s];
  }

  f32x4 oacc[8][2];                              // out_l^T [128 d][32 s]
  #pragma unroll
  for (int a = 0; a < 8; a++)
    #pragma unroll
    for (int c = 0; c < 2; c++) oacc[a][c] = f32x4{0.f, 0.f, 0.f, 0.f};

  for (int tt = 0; tt < 16; tt++) {
    const int tb = chunk * 1024 + tt * 64;
    f32x4 sacc[4][2];
    #pragma unroll
    for (int a = 0; a < 4; a++)
      #pragma unroll
      for (int c = 0; c < 2; c++) sacc[a][c] = f32x4{0.f, 0.f, 0.f, 0.f};
    #pragma unroll
    for (int ks = 0; ks < 4; ks++) {
      const int dof = ks * 32 + l4 * 8;
      bf16x8 aq[4], bk[2];
      #pragma unroll
      for (int ti = 0; ti < 4; ti++) aq[ti] = ldg8(qp + (size_t)(tb + ti * 16 + l15) * 128 + dof);
      #pragma unroll
      for (int si = 0; si < 2; si++) bk[si] = ldg8(kp + (size_t)(sbase + si * 16 + l15) * 128 + dof);
      #pragma unroll
      for (int ti = 0; ti < 4; ti++)
        #pragma unroll
        for (int si = 0; si < 2; si++)
          sacc[ti][si] = mfma16(aq[ti], bk[si], sacc[ti][si]);
    }
    // p = exp(clamp(score) - colmax) -> PT transposed [s][t]
    #pragma unroll
    for (int ti = 0; ti < 4; ti++)
      #pragma unroll
      for (int si = 0; si < 2; si++) {
        float e0 = __expf(clampf(sacc[ti][si][0]) - cm[si]);
        float e1 = __expf(clampf(sacc[ti][si][1]) - cm[si]);
        float e2 = __expf(clampf(sacc[ti][si][2]) - cm[si]);
        float e3 = __expf(clampf(sacc[ti][si][3]) - cm[si]);
        unsigned int* dst = (unsigned int*)(&PT[w][(si * 16 + l15) * 72 + ti * 16 + l4 * 4]);
        dst[0] = pack2(e0, e1);
        dst[1] = pack2(e2, e3);
      }
    __syncthreads();
    // out_l^T += val_v^T[d][t] @ P[t][s]
    #pragma unroll
    for (int kst = 0; kst < 2; kst++) {
      const int toff = tb + kst * 32 + l4 * 8;
      bf16x8 bp[2];
      #pragma unroll
      for (int nf = 0; nf < 2; nf++)
        bp[nf] = *(const bf16x8*)(&PT[w][(nf * 16 + l15) * 72 + kst * 32 + l4 * 8]);
      #pragma unroll
      for (int mf = 0; mf < 8; mf++) {
        bf16x8 av = ldg8(vp + (size_t)(mf * 16 + l15) * Tn + toff);
        #pragma unroll
        for (int nf = 0; nf < 2; nf++)
          oacc[mf][nf] = mfma16(av, bp[nf], oacc[mf][nf]);
      }
    }
    __syncthreads();
  }
  // scatter-accumulate olh[s][h*128+d] (fp32 atomics; 16 chunk-blocks contend)
  #pragma unroll
  for (int mf = 0; mf < 8; mf++)
    #pragma unroll
    for (int nf = 0; nf < 2; nf++) {
      const int s = sbase + nf * 16 + l15;
      const int d = mf * 16 + l4 * 4;
      float* dst = olh + (size_t)s * 1024 + h * 128 + d;
      #pragma unroll
      for (int i = 0; i < 4; i++) atomicAdd(dst + i, oacc[mf][nf][i] * ci[nf]);
    }
}

// ---------------- launch ----------------
extern "C" void kernel_launch(void* const* d_in, const int* in_sizes, int n_in,
                              void* d_out, int out_size, void* d_ws, size_t ws_size,
                              hipStream_t stream)
{
  (void)in_sizes; (void)n_in;
  const float* v        = (const float*)d_in[0];
  const float* l        = (const float*)d_in[1];
  const float* v_proj_w = (const float*)d_in[2];
  const float* v_proj_b = (const float*)d_in[3];
  const float* l_proj_w = (const float*)d_in[4];
  const float* l_proj_b = (const float*)d_in[5];
  const float* vv_w     = (const float*)d_in[6];
  const float* vv_b     = (const float*)d_in[7];
  const float* vl_w     = (const float*)d_in[8];
  const float* vl_b     = (const float*)d_in[9];
  const float* ov_w     = (const float*)d_in[10];
  const float* ov_b     = (const float*)d_in[11];
  const float* ol_w     = (const float*)d_in[12];
  const float* ol_b     = (const float*)d_in[13];

  char* ws = (char*)d_ws;
  size_t off = 0;
  auto alloc = [&](size_t bytes) -> char* {
    char* p = ws + off;
    off += (bytes + 255) & ~(size_t)255;
    return p;
  };

  // persistent across phases (~25.6 MB)
  bf16*  lb    = (bf16*)alloc((size_t)1024 * 768 * 2);
  bf16*  wqt   = (bf16*)alloc((size_t)1024 * 256 * 2);
  bf16*  wvvt  = (bf16*)alloc((size_t)1024 * 256 * 2);
  bf16*  wkt   = (bf16*)alloc((size_t)1024 * 768 * 2);
  bf16*  wvlt  = (bf16*)alloc((size_t)1024 * 768 * 2);
  bf16*  wovt  = (bf16*)alloc((size_t)256 * 1024 * 2);
  bf16*  wolt  = (bf16*)alloc((size_t)768 * 1024 * 2);
  bf16*  kh    = (bf16*)alloc((size_t)32 * 256 * 128 * 2);
  bf16*  vallT = (bf16*)alloc((size_t)32 * 128 * 256 * 2);
  float* olh   = (float*)alloc((size_t)1024 * 1024 * 4);
  bf16*  olhb  = (bf16*)alloc((size_t)1024 * 1024 * 2);
  // per-b phase scratch (~76 MB)
  bf16*  vb_b  = (bf16*)alloc((size_t)16384 * 256 * 2);           // 8 MB
  bf16*  qh_b  = (bf16*)alloc((size_t)8 * 16384 * 128 * 2);       // 32 MB
  bf16*  buf   = (bf16*)alloc((size_t)8 * 128 * 16384 * 2);       // 32 MB (ovh <-> valvT)
  float* cmaxp = (float*)alloc((size_t)8 * 256 * 256 * 4);        // 2 MB
  float* csump = (float*)alloc((size_t)8 * 256 * 256 * 4);        // 2 MB
  float* cmax  = (float*)alloc((size_t)2048 * 4);
  float* cinv  = (float*)alloc((size_t)2048 * 4);
  // total ~93.5 MB

  if (off > ws_size) {
    // sentinel: NaN-fill output so "ws too small" is distinguishable from "not written"
    hipMemsetAsync(d_out, 0xFF, (size_t)out_size * 4, stream);
    return;
  }

  hipMemsetAsync(olh, 0, (size_t)1024 * 1024 * 4, stream);

  cast_misc<<<dim3(3072, 7), 256, 0, stream>>>(l, lb, v_proj_w, wqt, vv_w, wvvt,
                                               l_proj_w, wkt, vl_w, wvlt, ov_w, wovt, ol_w, wolt);
  // kh + vallT for all b (small)
  gemm_kern<1><<<dim3(8, 8, 2), 256, 0, stream>>>(lb, wkt, wvlt, l_proj_b, vl_b, kh, vallT, 0);

  for (int b = 0; b < 4; b++) {
    const bf16* kh_b    = kh    + (size_t)b * 8 * Sn * 128;
    const bf16* vallT_b = vallT + (size_t)b * 8 * 128 * Sn;
    cast_f32_bf16_v4<<<4096, 256, 0, stream>>>(v + (size_t)b * 16384 * 256, vb_b, 1048576);
    // q heads (z=0 only)
    gemm_kern<0><<<dim3(128, 8, 1), 256, 0, stream>>>(vb_b, wqt, wvvt, v_proj_b, vv_b, qh_b, nullptr, 0);
    // row pass -> buf(=out_v heads [Tn][En]) + column partials
    attn_row<<<dim3(256, 8), 256, 0, stream>>>(qh_b, kh_b, vallT_b, buf, cmaxp, csump);
    // out0 rows for this b
    gemm_kern<2><<<dim3(128, 2, 1), 256, 0, stream>>>(buf, wovt, wovt, ov_b, ov_b,
                                                      (float*)d_out + (size_t)b * 16384 * 256, nullptr, 0);
    // val_v^T heads (z=1 only) into buf (ovh no longer needed)
    gemm_kern<0><<<dim3(128, 8, 1), 256, 0, stream>>>(vb_b, wqt, wvvt, v_proj_b, vv_b, nullptr, buf, 1);
    col_reduce<<<512, 256, 0, stream>>>(cmaxp, csump, cmax, cinv);
    attn_col<<<dim3(16, 8, 2), 256, 0, stream>>>(qh_b, kh_b, buf, cmax, cinv,
                                                 olh + (size_t)b * 256 * 1024);
  }

  cast_f32_bf16_v4<<<1024, 256, 0, stream>>>(olh, olhb, 262144);
  gemm_kern<3><<<dim3(8, 6, 1), 256, 0, stream>>>(olhb, wolt, wolt, ol_b, ol_b,
                                                  (float*)d_out + 16777216, nullptr, 0);
}